// Round 1
// baseline (1342.350 us; speedup 1.0000x reference)
//
#include <hip/hip_runtime.h>
#include <hip/hip_bf16.h>

#define D 128
#define EPS 1e-5f

// ---------------- K1: LayerNorm + ReLU (one block = one node, 128 threads) ----
__global__ void k_ln_relu(const float* __restrict__ x, const int* __restrict__ node_type,
                          const float* __restrict__ gamma, const float* __restrict__ beta,
                          float* __restrict__ y, int N) {
    int n = blockIdx.x;
    int d = threadIdx.x;            // 128 threads
    float v = x[(size_t)n * D + d];
    float s = v, s2 = v * v;
    #pragma unroll
    for (int off = 32; off > 0; off >>= 1) {
        s  += __shfl_xor(s,  off, 64);
        s2 += __shfl_xor(s2, off, 64);
    }
    __shared__ float red[4];
    int w = d >> 6;
    if ((d & 63) == 0) { red[w] = s; red[2 + w] = s2; }
    __syncthreads();
    float S  = red[0] + red[1];
    float S2 = red[2] + red[3];
    float mu  = S * (1.0f / D);
    float var = S2 * (1.0f / D) - mu * mu;
    float inv = rsqrtf(var + EPS);
    int t = node_type[n];
    float yn = (v - mu) * inv * gamma[t * D + d] + beta[t * D + d];
    y[(size_t)n * D + d] = fmaxf(yn, 0.0f);
}

// ---------------- K2: h[r] = y @ W_rel[r] (r<8), agg = y @ W_root (r==8) -------
// grid (ceil(N/16), 9), block 256. 16-node tile in LDS; each thread: 1 col x 8 nodes.
__global__ void k_rel_gemm(const float* __restrict__ y, const float* __restrict__ W_rel,
                           const float* __restrict__ W_root,
                           __hip_bfloat16* __restrict__ h, float* __restrict__ agg, int N) {
    __shared__ float ylds[16 * D];
    int nb  = blockIdx.x * 16;
    int tid = threadIdx.x;
    #pragma unroll
    for (int i = 0; i < 8; ++i) {
        int k = tid + i * 256;
        int n = nb + (k >> 7);
        ylds[k] = (n < N) ? y[(size_t)n * D + (k & (D - 1))] : 0.0f;
    }
    __syncthreads();
    int c = tid & (D - 1);
    int g = tid >> 7;                 // 0 or 1 -> nodes [g*8, g*8+8)
    int r = blockIdx.y;
    const float* Wp = (r < 8) ? (W_rel + (size_t)r * D * D + c) : (W_root + c);
    float acc[8] = {0.f,0.f,0.f,0.f,0.f,0.f,0.f,0.f};
    const float* yb = &ylds[g * 8 * D];
    #pragma unroll 4
    for (int d = 0; d < D; ++d) {
        float w = Wp[(size_t)d * D];
        #pragma unroll
        for (int i = 0; i < 8; ++i)
            acc[i] += yb[i * D + d] * w;
    }
    if (r < 8) {
        #pragma unroll
        for (int i = 0; i < 8; ++i) {
            int n = nb + g * 8 + i;
            if (n < N) h[((size_t)r * N + n) * D + c] = __float2bfloat16(acc[i]);
        }
    } else {
        #pragma unroll
        for (int i = 0; i < 8; ++i) {
            int n = nb + g * 8 + i;
            if (n < N) agg[(size_t)n * D + c] = acc[i];
        }
    }
}

// ---------------- K3: per-edge gather + atomic scatter-add --------------------
// block 256 = 2 edges x 128 threads
__global__ void k_edge(const __hip_bfloat16* __restrict__ h,
                       const int* __restrict__ esrc, const int* __restrict__ edst,
                       const int* __restrict__ etyp,
                       float* __restrict__ agg, int E, int N) {
    int e = blockIdx.x * 2 + (threadIdx.x >> 7);
    if (e >= E) return;
    int d = threadIdx.x & (D - 1);
    int s = esrc[e], v = edst[e], r = etyp[e];
    float val = __bfloat162float(h[((size_t)r * N + s) * D + d]);
    atomicAdd(&agg[(size_t)v * D + d], val);
}

// ---------------- K4: x2 = x + agg (in-place over agg); LN2+ReLU -> y2 --------
__global__ void k_res_ln_relu(const float* __restrict__ x, float* __restrict__ agg,
                              const int* __restrict__ node_type,
                              const float* __restrict__ gamma, const float* __restrict__ beta,
                              float* __restrict__ y2, int N) {
    int n = blockIdx.x;
    int d = threadIdx.x;
    size_t idx = (size_t)n * D + d;
    float v = x[idx] + agg[idx];
    float s = v, s2 = v * v;
    #pragma unroll
    for (int off = 32; off > 0; off >>= 1) {
        s  += __shfl_xor(s,  off, 64);
        s2 += __shfl_xor(s2, off, 64);
    }
    __shared__ float red[4];
    int w = d >> 6;
    if ((d & 63) == 0) { red[w] = s; red[2 + w] = s2; }
    __syncthreads();
    float S  = red[0] + red[1];
    float S2 = red[2] + red[3];
    float mu  = S * (1.0f / D);
    float var = S2 * (1.0f / D) - mu * mu;
    float inv = rsqrtf(var + EPS);
    int t = node_type[n];
    float yn = (v - mu) * inv * gamma[t * D + d] + beta[t * D + d];
    agg[idx] = v;                     // x2 stored in-place
    y2[idx]  = fmaxf(yn, 0.0f);
}

// ---------------- bucketing: hist / offsets / scatter -------------------------
__global__ void k_hist(const int* __restrict__ nt, int* __restrict__ hist, int N) {
    int n = blockIdx.x * blockDim.x + threadIdx.x;
    if (n < N) atomicAdd(&hist[nt[n]], 1);
}
__global__ void k_off(int* __restrict__ hist) {   // hist[0..3] -> cursor hist[4..7]
    int o = 0;
    for (int t = 0; t < 4; ++t) { int c = hist[t]; hist[4 + t] = o; o += c; }
}
__global__ void k_scatter(const int* __restrict__ nt, int* __restrict__ cursor,
                          int* __restrict__ perm, int N) {
    int n = blockIdx.x * blockDim.x + threadIdx.x;
    if (n < N) { int p = atomicAdd(&cursor[nt[n]], 1); perm[p] = n; }
}

// ---------------- K5: per-type MLP + residual, tiled over perm ----------------
// grid ceil(N/16), block 256
__global__ void k_mlp(const float* __restrict__ y2, const float* __restrict__ x2,
                      const int* __restrict__ perm, const int* __restrict__ node_type,
                      const float* __restrict__ W_mlp, const float* __restrict__ b_mlp,
                      float* __restrict__ out, int N) {
    __shared__ float ylds[16 * D];
    __shared__ int nid[16];
    __shared__ int nty[16];
    int tid  = threadIdx.x;
    int base = blockIdx.x * 16;
    if (tid < 16) {
        int bi = base + tid;
        int n  = (bi < N) ? perm[bi] : 0;
        nid[tid] = n;
        nty[tid] = node_type[n];
    }
    __syncthreads();
    #pragma unroll
    for (int i = 0; i < 8; ++i) {
        int k = tid + i * 256;
        ylds[k] = y2[(size_t)nid[k >> 7] * D + (k & (D - 1))];
    }
    int t0 = nty[0];
    bool uni = true;
    #pragma unroll
    for (int i = 1; i < 16; ++i) uni = uni && (nty[i] == t0);
    __syncthreads();

    int c = tid & (D - 1);
    int g = tid >> 7;
    float acc[8] = {0.f,0.f,0.f,0.f,0.f,0.f,0.f,0.f};
    const float* yb = &ylds[g * 8 * D];
    if (uni) {
        const float* Wp = W_mlp + (size_t)t0 * D * D + c;
        #pragma unroll 4
        for (int d = 0; d < D; ++d) {
            float w = Wp[(size_t)d * D];
            #pragma unroll
            for (int i = 0; i < 8; ++i)
                acc[i] += yb[i * D + d] * w;
        }
    } else {
        // rare: tile spans a type boundary (<=3 tiles total)
        for (int i = 0; i < 8; ++i) {
            const float* Wp = W_mlp + (size_t)nty[g * 8 + i] * D * D + c;
            float a = 0.f;
            for (int d = 0; d < D; ++d) a += yb[i * D + d] * Wp[(size_t)d * D];
            acc[i] = a;
        }
    }
    #pragma unroll
    for (int i = 0; i < 8; ++i) {
        int bi = base + g * 8 + i;
        if (bi < N) {
            int n = nid[g * 8 + i];
            int t = nty[g * 8 + i];
            out[(size_t)n * D + c] = x2[(size_t)n * D + c] + acc[i] + b_mlp[t * D + c];
        }
    }
}

// ---------------- launch ------------------------------------------------------
extern "C" void kernel_launch(void* const* d_in, const int* in_sizes, int n_in,
                              void* d_out, int out_size, void* d_ws, size_t ws_size,
                              hipStream_t stream) {
    const float* x          = (const float*)d_in[0];
    const int*   esrc       = (const int*)d_in[1];
    const int*   edst       = (const int*)d_in[2];
    const int*   ntyp       = (const int*)d_in[3];
    const int*   etyp       = (const int*)d_in[4];
    const float* conv_gamma = (const float*)d_in[5];
    const float* conv_beta  = (const float*)d_in[6];
    const float* W_rel      = (const float*)d_in[7];
    const float* W_root     = (const float*)d_in[8];
    const float* mlp_gamma  = (const float*)d_in[9];
    const float* mlp_beta   = (const float*)d_in[10];
    const float* W_mlp      = (const float*)d_in[11];
    const float* b_mlp      = (const float*)d_in[12];
    float* out = (float*)d_out;

    int N = in_sizes[0] / D;
    int E = in_sizes[1];

    // ws layout (all 256B-aligned): y | h(bf16) | agg | perm | hist(8 ints)
    char* p = (char*)d_ws;
    float* y = (float*)p;                 p += (size_t)N * D * sizeof(float);
    __hip_bfloat16* h = (__hip_bfloat16*)p; p += (size_t)8 * N * D * sizeof(__hip_bfloat16);
    float* agg = (float*)p;               p += (size_t)N * D * sizeof(float);
    int* perm = (int*)p;                  p += (size_t)((N + 63) / 64) * 64 * sizeof(int);
    int* hist = (int*)p;                  p += 64;

    hipMemsetAsync(hist, 0, 4 * sizeof(int), stream);

    k_ln_relu<<<N, D, 0, stream>>>(x, ntyp, conv_gamma, conv_beta, y, N);

    dim3 g2((N + 15) / 16, 9);
    k_rel_gemm<<<g2, 256, 0, stream>>>(y, W_rel, W_root, h, agg, N);

    k_hist<<<(N + 255) / 256, 256, 0, stream>>>(ntyp, hist, N);
    k_off<<<1, 1, 0, stream>>>(hist);
    k_scatter<<<(N + 255) / 256, 256, 0, stream>>>(ntyp, hist + 4, perm, N);

    k_edge<<<(E + 1) / 2, 256, 0, stream>>>(h, esrc, edst, etyp, agg, E, N);

    k_res_ln_relu<<<N, D, 0, stream>>>(x, agg, ntyp, mlp_gamma, mlp_beta, y, N);

    k_mlp<<<(N + 15) / 16, 256, 0, stream>>>(y, agg, perm, ntyp, W_mlp, b_mlp, out, N);
}

// Round 2
// 926.664 us; speedup vs baseline: 1.4486x; 1.4486x over previous
//
#include <hip/hip_runtime.h>
#include <hip/hip_bf16.h>

#define D 128
#define EPS 1e-5f

typedef __attribute__((ext_vector_type(8))) short short8;
typedef __attribute__((ext_vector_type(4))) float float4v;

__device__ inline ushort f2bf(float f) {
    __hip_bfloat16 b = __float2bfloat16(f);
    return *reinterpret_cast<ushort*>(&b);
}
__device__ inline float bf_lo(uint u) { return __uint_as_float(u << 16); }
__device__ inline float bf_hi(uint u) { return __uint_as_float(u & 0xffff0000u); }

// ---------- K1: LN1 + ReLU, fp32 in -> bf16 out. One wave per node. ----------
__global__ void k_ln1(const float* __restrict__ x, const int* __restrict__ ntp,
                      const float* __restrict__ gamma, const float* __restrict__ beta,
                      ushort* __restrict__ y, int N) {
    int n = blockIdx.x * 4 + (threadIdx.x >> 6);
    if (n >= N) return;
    int l = threadIdx.x & 63;
    float2 v = *(const float2*)(x + (size_t)n * D + 2 * l);
    float s = v.x + v.y, s2 = v.x * v.x + v.y * v.y;
    #pragma unroll
    for (int o = 32; o; o >>= 1) { s += __shfl_xor(s, o, 64); s2 += __shfl_xor(s2, o, 64); }
    float mu = s * (1.0f / D);
    float var = s2 * (1.0f / D) - mu * mu;
    float inv = rsqrtf(var + EPS);
    int t = ntp[n];
    float2 g = *(const float2*)(gamma + t * D + 2 * l);
    float2 b = *(const float2*)(beta + t * D + 2 * l);
    float a0 = fmaxf((v.x - mu) * inv * g.x + b.x, 0.0f);
    float a1 = fmaxf((v.y - mu) * inv * g.y + b.y, 0.0f);
    ((uint*)(y + (size_t)n * D))[l] = ((uint)f2bf(a1) << 16) | f2bf(a0);
}

// ---------- K2: convert 13 weight matrices to bf16, TRANSPOSED: Wt[m][n][k] ---
// block m in 0..12: 0..7 = W_rel[r], 8 = W_root, 9..12 = W_mlp[t]
__global__ void k_cvt(const float* __restrict__ Wrel, const float* __restrict__ Wroot,
                      const float* __restrict__ Wmlp, ushort* __restrict__ Wt) {
    __shared__ ushort t[128][136];
    int m = blockIdx.x;
    const float* src = (m < 8) ? Wrel + (size_t)m * D * D
                     : (m == 8) ? Wroot : Wmlp + (size_t)(m - 9) * D * D;
    for (int i = threadIdx.x; i < D * D; i += 256) {
        int k = i >> 7, n = i & 127;
        t[n][k] = f2bf(src[i]);
    }
    __syncthreads();
    ushort* dst = Wt + (size_t)m * D * D;
    for (int i = threadIdx.x; i < D * D; i += 256) dst[i] = t[i >> 7][i & 127];
}

// ---------- K3: MFMA GEMM. mat<8: h[mat] = y @ W_rel[mat] (bf16 out);
//                          mat==8: agg = y @ W_root (fp32 out). -----------------
// grid (ceil(N/64), 9), block 256. Wave = 16 rows x 128 cols. No LDS.
__global__ void k_gemm(const ushort* __restrict__ y, const ushort* __restrict__ Wt,
                       ushort* __restrict__ h, float* __restrict__ agg, int N) {
    int wave = threadIdx.x >> 6;
    int lane = threadIdx.x & 63;
    int quad = lane >> 4;
    int mat = blockIdx.y;
    int base = blockIdx.x * 64 + wave * 16;
    int mrow = base + (lane & 15);
    int mcl = min(mrow, N - 1);
    short8 a[4];
    const ushort* yrow = y + (size_t)mcl * D + quad * 8;
    #pragma unroll
    for (int ks = 0; ks < 4; ++ks) a[ks] = *(const short8*)(yrow + ks * 32);
    const ushort* Wb = Wt + (size_t)mat * D * D;
    #pragma unroll
    for (int nt = 0; nt < 8; ++nt) {
        int n0 = nt * 16;
        float4v acc = {0.f, 0.f, 0.f, 0.f};
        const ushort* wrow = Wb + (size_t)(n0 + (lane & 15)) * D + quad * 8;
        #pragma unroll
        for (int ks = 0; ks < 4; ++ks) {
            short8 b = *(const short8*)(wrow + ks * 32);
            acc = __builtin_amdgcn_mfma_f32_16x16x32_bf16(a[ks], b, acc, 0, 0, 0);
        }
        int col = n0 + (lane & 15);
        if (mat < 8) {
            #pragma unroll
            for (int r = 0; r < 4; ++r) {
                int row = base + quad * 4 + r;
                if (row < N) h[((size_t)mat * N + row) * D + col] = f2bf(acc[r]);
            }
        } else {
            #pragma unroll
            for (int r = 0; r < 4; ++r) {
                int row = base + quad * 4 + r;
                if (row < N) agg[(size_t)row * D + col] = acc[r];
            }
        }
    }
}

// ---------- edge bucketing: hist, scan, scatter -------------------------------
__global__ void k_ehist(const int* __restrict__ edst, int* __restrict__ hist, int E) {
    int e = blockIdx.x * blockDim.x + threadIdx.x;
    if (e < E) atomicAdd(&hist[edst[e]], 1);
}
// 1 block x 1024 threads: exclusive scan of hist[0..N) -> offs[0..N], cursor copy
__global__ void k_scan(const int* __restrict__ hist, int* __restrict__ offs,
                       int* __restrict__ cursor, int N) {
    __shared__ int ps[1024];
    int tid = threadIdx.x;
    int chunk = (N + 1023) / 1024;
    int s0 = tid * chunk;
    int s = 0;
    for (int i = 0; i < chunk; ++i) { int idx = s0 + i; if (idx < N) s += hist[idx]; }
    ps[tid] = s;
    __syncthreads();
    for (int off = 1; off < 1024; off <<= 1) {
        int v = (tid >= off) ? ps[tid - off] : 0;
        __syncthreads();
        ps[tid] += v;
        __syncthreads();
    }
    int run = tid ? ps[tid - 1] : 0;
    for (int i = 0; i < chunk; ++i) {
        int idx = s0 + i;
        if (idx < N) { offs[idx] = run; cursor[idx] = run; run += hist[idx]; }
    }
    if (tid == 1023) offs[N] = ps[1023];
}
__global__ void k_escatter(const int* __restrict__ edst, int* __restrict__ cursor,
                           int* __restrict__ eperm, int E) {
    int e = blockIdx.x * blockDim.x + threadIdx.x;
    if (e < E) { int p = atomicAdd(&cursor[edst[e]], 1); eperm[p] = e; }
}

// ---------- K4: per-dst message agg + residual + LN2 + ReLU (one wave/dst) ----
// agg in: root contribution. agg out: x2 = x + root + sum(msg). y2 out: bf16.
__global__ void k_edge_ln(const ushort* __restrict__ h, const float* __restrict__ x,
                          float* __restrict__ agg,
                          const int* __restrict__ offs, const int* __restrict__ eperm,
                          const int* __restrict__ esrc, const int* __restrict__ etyp,
                          const int* __restrict__ ntp,
                          const float* __restrict__ gamma, const float* __restrict__ beta,
                          ushort* __restrict__ y2, int N) {
    int v = blockIdx.x * 4 + (threadIdx.x >> 6);
    if (v >= N) return;
    int l = threadIdx.x & 63;
    float2 acc = *(const float2*)(agg + (size_t)v * D + 2 * l);
    int e0 = offs[v], e1 = offs[v + 1];
    for (int j = e0; j < e1; ++j) {
        int e = eperm[j];
        int s = esrc[e], r = etyp[e];
        uint u = ((const uint*)(h + ((size_t)r * N + s) * D))[l];
        acc.x += bf_lo(u);
        acc.y += bf_hi(u);
    }
    float2 xv = *(const float2*)(x + (size_t)v * D + 2 * l);
    float2 x2v = {xv.x + acc.x, xv.y + acc.y};
    *(float2*)(agg + (size_t)v * D + 2 * l) = x2v;
    float s = x2v.x + x2v.y, s2 = x2v.x * x2v.x + x2v.y * x2v.y;
    #pragma unroll
    for (int o = 32; o; o >>= 1) { s += __shfl_xor(s, o, 64); s2 += __shfl_xor(s2, o, 64); }
    float mu = s * (1.0f / D);
    float var = s2 * (1.0f / D) - mu * mu;
    float inv = rsqrtf(var + EPS);
    int t = ntp[v];
    float2 g = *(const float2*)(gamma + t * D + 2 * l);
    float2 b = *(const float2*)(beta + t * D + 2 * l);
    float a0 = fmaxf((x2v.x - mu) * inv * g.x + b.x, 0.0f);
    float a1 = fmaxf((x2v.y - mu) * inv * g.y + b.y, 0.0f);
    ((uint*)(y2 + (size_t)v * D))[l] = ((uint)f2bf(a1) << 16) | f2bf(a0);
}

// ---------- node-type bucketing (64-aligned) ----------------------------------
// small layout (ints): [0..3] thist, [4..7] cursor4, [8..12] start[5], [16..] tob
__global__ void k_nhist(const int* __restrict__ ntp, int* __restrict__ small, int N) {
    __shared__ int c[4];
    if (threadIdx.x < 4) c[threadIdx.x] = 0;
    __syncthreads();
    int n = blockIdx.x * blockDim.x + threadIdx.x;
    if (n < N) atomicAdd(&c[ntp[n]], 1);
    __syncthreads();
    if (threadIdx.x < 4 && c[threadIdx.x]) atomicAdd(&small[threadIdx.x], c[threadIdx.x]);
}
__global__ void k_prep(int* __restrict__ small, int gridMlp) {
    __shared__ int st[5];
    if (threadIdx.x == 0) {
        int o = 0;
        for (int t = 0; t < 4; ++t) {
            small[8 + t] = o;
            st[t] = o;
            int pad = (small[t] + 63) & ~63;
            o += pad;
        }
        small[12] = o;
        st[4] = o;
    }
    __syncthreads();
    int* tob = small + 16;
    for (int b = threadIdx.x; b < gridMlp; b += blockDim.x) {
        int b64 = b * 64;
        int t = -1;
        for (int i = 0; i < 4; ++i)
            if (b64 >= st[i] && b64 < st[i + 1]) t = i;
        tob[b] = t;
    }
}
__global__ void k_nscatter(const int* __restrict__ ntp, int* __restrict__ small,
                           int* __restrict__ perm_pad, int N) {
    int n = blockIdx.x * blockDim.x + threadIdx.x;
    if (n < N) {
        int t = ntp[n];
        int p = small[8 + t] + atomicAdd(&small[4 + t], 1);
        perm_pad[p] = n;
    }
}

// ---------- K5: MLP MFMA + residual + bias, type-uniform 64-row blocks --------
__global__ void k_mlp(const ushort* __restrict__ y2, const float* __restrict__ x2,
                      const int* __restrict__ perm_pad, const int* __restrict__ small,
                      const ushort* __restrict__ Wt, const float* __restrict__ bmlp,
                      float* __restrict__ out, int N) {
    int t = small[16 + blockIdx.x];
    if (t < 0) return;
    int wave = threadIdx.x >> 6;
    int lane = threadIdx.x & 63;
    int quad = lane >> 4;
    int base = blockIdx.x * 64 + wave * 16;
    int node = perm_pad[base + (lane & 15)];
    int arow = node < 0 ? 0 : node;
    short8 a[4];
    const ushort* yrow = y2 + (size_t)arow * D + quad * 8;
    #pragma unroll
    for (int ks = 0; ks < 4; ++ks) a[ks] = *(const short8*)(yrow + ks * 32);
    int srow[4];
    #pragma unroll
    for (int r = 0; r < 4; ++r) srow[r] = perm_pad[base + quad * 4 + r];
    const ushort* Wb = Wt + (size_t)(9 + t) * D * D;
    #pragma unroll
    for (int nt = 0; nt < 8; ++nt) {
        int n0 = nt * 16;
        float4v acc = {0.f, 0.f, 0.f, 0.f};
        const ushort* wrow = Wb + (size_t)(n0 + (lane & 15)) * D + quad * 8;
        #pragma unroll
        for (int ks = 0; ks < 4; ++ks) {
            short8 b = *(const short8*)(wrow + ks * 32);
            acc = __builtin_amdgcn_mfma_f32_16x16x32_bf16(a[ks], b, acc, 0, 0, 0);
        }
        int col = n0 + (lane & 15);
        float bm = bmlp[t * D + col];
        #pragma unroll
        for (int r = 0; r < 4; ++r) {
            if (srow[r] >= 0)
                out[(size_t)srow[r] * D + col] =
                    x2[(size_t)srow[r] * D + col] + acc[r] + bm;
        }
    }
}

// ---------- launch ------------------------------------------------------------
extern "C" void kernel_launch(void* const* d_in, const int* in_sizes, int n_in,
                              void* d_out, int out_size, void* d_ws, size_t ws_size,
                              hipStream_t stream) {
    const float* x          = (const float*)d_in[0];
    const int*   esrc       = (const int*)d_in[1];
    const int*   edst       = (const int*)d_in[2];
    const int*   ntyp       = (const int*)d_in[3];
    const int*   etyp       = (const int*)d_in[4];
    const float* conv_gamma = (const float*)d_in[5];
    const float* conv_beta  = (const float*)d_in[6];
    const float* W_rel      = (const float*)d_in[7];
    const float* W_root     = (const float*)d_in[8];
    const float* mlp_gamma  = (const float*)d_in[9];
    const float* mlp_beta   = (const float*)d_in[10];
    const float* W_mlp      = (const float*)d_in[11];
    const float* b_mlp      = (const float*)d_in[12];
    float* out = (float*)d_out;

    int N = in_sizes[0] / D;
    int E = in_sizes[1];
    int gridMlp = (N + 252 + 63) / 64;

    // ws layout, all 256B aligned
    char* p = (char*)d_ws;
    auto take = [&p](size_t bytes) { char* q = p; p += (bytes + 255) & ~(size_t)255; return q; };
    ushort* y       = (ushort*)take((size_t)N * D * 2);
    ushort* y2      = (ushort*)take((size_t)N * D * 2);
    ushort* h       = (ushort*)take((size_t)8 * N * D * 2);
    float*  agg     = (float*)take((size_t)N * D * 4);
    ushort* Wt      = (ushort*)take((size_t)13 * D * D * 2);
    int*    hist    = (int*)take((size_t)N * 4);
    int*    offs    = (int*)take((size_t)(N + 1) * 4);
    int*    cursor  = (int*)take((size_t)N * 4);
    int*    eperm   = (int*)take((size_t)E * 4);
    int*    permpad = (int*)take((size_t)(N + 256) * 4);
    int*    small   = (int*)take((size_t)(16 + gridMlp) * 4);

    hipMemsetAsync(hist, 0, (size_t)N * 4, stream);
    hipMemsetAsync(small, 0, 16 * 4, stream);
    hipMemsetAsync(permpad, 0xFF, (size_t)(N + 256) * 4, stream);

    k_ln1<<<(N + 3) / 4, 256, 0, stream>>>(x, ntyp, conv_gamma, conv_beta, y, N);
    k_cvt<<<13, 256, 0, stream>>>(W_rel, W_root, W_mlp, Wt);

    k_ehist<<<(E + 255) / 256, 256, 0, stream>>>(edst, hist, E);
    k_scan<<<1, 1024, 0, stream>>>(hist, offs, cursor, N);
    k_escatter<<<(E + 255) / 256, 256, 0, stream>>>(edst, cursor, eperm, E);

    k_nhist<<<(N + 255) / 256, 256, 0, stream>>>(ntyp, small, N);
    k_prep<<<1, 256, 0, stream>>>(small, gridMlp);
    k_nscatter<<<(N + 255) / 256, 256, 0, stream>>>(ntyp, small, permpad, N);

    dim3 g2((N + 63) / 64, 9);
    k_gemm<<<g2, 256, 0, stream>>>(y, Wt, h, agg, N);

    k_edge_ln<<<(N + 3) / 4, 256, 0, stream>>>(h, x, agg, offs, eperm, esrc, etyp,
                                               ntyp, mlp_gamma, mlp_beta, y2, N);

    k_mlp<<<gridMlp, 256, 0, stream>>>(y2, agg, permpad, small, Wt, b_mlp, out, N);
}

// Round 3
// 614.198 us; speedup vs baseline: 2.1855x; 1.5087x over previous
//
#include <hip/hip_runtime.h>
#include <hip/hip_bf16.h>

#define D 128
#define EPS 1e-5f

typedef __attribute__((ext_vector_type(8))) short short8;
typedef __attribute__((ext_vector_type(4))) float float4v;

__device__ inline ushort f2bf(float f) {
    __hip_bfloat16 b = __float2bfloat16(f);
    return *reinterpret_cast<ushort*>(&b);
}
__device__ inline float bf_lo(uint u) { return __uint_as_float(u << 16); }
__device__ inline float bf_hi(uint u) { return __uint_as_float(u & 0xffff0000u); }

// ---------- K1: LN1 + ReLU, fp32 in -> bf16 out. One wave per node. ----------
__global__ void k_ln1(const float* __restrict__ x, const int* __restrict__ ntp,
                      const float* __restrict__ gamma, const float* __restrict__ beta,
                      ushort* __restrict__ y, int N) {
    int n = blockIdx.x * 4 + (threadIdx.x >> 6);
    if (n >= N) return;
    int l = threadIdx.x & 63;
    float2 v = *(const float2*)(x + (size_t)n * D + 2 * l);
    float s = v.x + v.y, s2 = v.x * v.x + v.y * v.y;
    #pragma unroll
    for (int o = 32; o; o >>= 1) { s += __shfl_xor(s, o, 64); s2 += __shfl_xor(s2, o, 64); }
    float mu = s * (1.0f / D);
    float var = s2 * (1.0f / D) - mu * mu;
    float inv = rsqrtf(var + EPS);
    int t = ntp[n];
    float2 g = *(const float2*)(gamma + t * D + 2 * l);
    float2 b = *(const float2*)(beta + t * D + 2 * l);
    float a0 = fmaxf((v.x - mu) * inv * g.x + b.x, 0.0f);
    float a1 = fmaxf((v.y - mu) * inv * g.y + b.y, 0.0f);
    ((uint*)(y + (size_t)n * D))[l] = ((uint)f2bf(a1) << 16) | f2bf(a0);
}

// ---------- K2: convert 13 weight matrices to bf16, TRANSPOSED: Wt[m][n][k] ---
__global__ void k_cvt(const float* __restrict__ Wrel, const float* __restrict__ Wroot,
                      const float* __restrict__ Wmlp, ushort* __restrict__ Wt) {
    __shared__ ushort t[128][136];
    int m = blockIdx.x;
    const float* src = (m < 8) ? Wrel + (size_t)m * D * D
                     : (m == 8) ? Wroot : Wmlp + (size_t)(m - 9) * D * D;
    for (int i = threadIdx.x; i < D * D; i += 256) {
        int k = i >> 7, n = i & 127;
        t[n][k] = f2bf(src[i]);
    }
    __syncthreads();
    ushort* dst = Wt + (size_t)m * D * D;
    for (int i = threadIdx.x; i < D * D; i += 256) dst[i] = t[i >> 7][i & 127];
}

// ---------- K3: MFMA GEMM. mat<8: h[mat] = y @ W_rel[mat] (bf16 out);
//                          mat==8: agg = y @ W_root (fp32 out). -----------------
__global__ void k_gemm(const ushort* __restrict__ y, const ushort* __restrict__ Wt,
                       ushort* __restrict__ h, float* __restrict__ agg, int N) {
    int wave = threadIdx.x >> 6;
    int lane = threadIdx.x & 63;
    int quad = lane >> 4;
    int mat = blockIdx.y;
    int base = blockIdx.x * 64 + wave * 16;
    int mrow = base + (lane & 15);
    int mcl = min(mrow, N - 1);
    short8 a[4];
    const ushort* yrow = y + (size_t)mcl * D + quad * 8;
    #pragma unroll
    for (int ks = 0; ks < 4; ++ks) a[ks] = *(const short8*)(yrow + ks * 32);
    const ushort* Wb = Wt + (size_t)mat * D * D;
    #pragma unroll
    for (int nt = 0; nt < 8; ++nt) {
        int n0 = nt * 16;
        float4v acc = {0.f, 0.f, 0.f, 0.f};
        const ushort* wrow = Wb + (size_t)(n0 + (lane & 15)) * D + quad * 8;
        #pragma unroll
        for (int ks = 0; ks < 4; ++ks) {
            short8 b = *(const short8*)(wrow + ks * 32);
            acc = __builtin_amdgcn_mfma_f32_16x16x32_bf16(a[ks], b, acc, 0, 0, 0);
        }
        int col = n0 + (lane & 15);
        if (mat < 8) {
            #pragma unroll
            for (int r = 0; r < 4; ++r) {
                int row = base + quad * 4 + r;
                if (row < N) h[((size_t)mat * N + row) * D + col] = f2bf(acc[r]);
            }
        } else {
            #pragma unroll
            for (int r = 0; r < 4; ++r) {
                int row = base + quad * 4 + r;
                if (row < N) agg[(size_t)row * D + col] = acc[r];
            }
        }
    }
}

// ---------- edge bucketing: hist, scan, scatter -------------------------------
__global__ void k_ehist(const int* __restrict__ edst, int* __restrict__ hist, int E) {
    int e = blockIdx.x * blockDim.x + threadIdx.x;
    if (e < E) atomicAdd(&hist[edst[e]], 1);
}
__global__ void k_scan(const int* __restrict__ hist, int* __restrict__ offs,
                       int* __restrict__ cursor, int N) {
    __shared__ int ps[1024];
    int tid = threadIdx.x;
    int chunk = (N + 1023) / 1024;
    int s0 = tid * chunk;
    int s = 0;
    for (int i = 0; i < chunk; ++i) { int idx = s0 + i; if (idx < N) s += hist[idx]; }
    ps[tid] = s;
    __syncthreads();
    for (int off = 1; off < 1024; off <<= 1) {
        int v = (tid >= off) ? ps[tid - off] : 0;
        __syncthreads();
        ps[tid] += v;
        __syncthreads();
    }
    int run = tid ? ps[tid - 1] : 0;
    for (int i = 0; i < chunk; ++i) {
        int idx = s0 + i;
        if (idx < N) { offs[idx] = run; cursor[idx] = run; run += hist[idx]; }
    }
    if (tid == 1023) offs[N] = ps[1023];
}
__global__ void k_escatter(const int* __restrict__ edst, int* __restrict__ cursor,
                           int* __restrict__ eperm, int E) {
    int e = blockIdx.x * blockDim.x + threadIdx.x;
    if (e < E) { int p = atomicAdd(&cursor[edst[e]], 1); eperm[p] = e; }
}

// ---------- K4: per-dst message agg + residual + LN2 + ReLU (one wave/dst) ----
__global__ void k_edge_ln(const ushort* __restrict__ h, const float* __restrict__ x,
                          float* __restrict__ agg,
                          const int* __restrict__ offs, const int* __restrict__ eperm,
                          const int* __restrict__ esrc, const int* __restrict__ etyp,
                          const int* __restrict__ ntp,
                          const float* __restrict__ gamma, const float* __restrict__ beta,
                          ushort* __restrict__ y2, int N) {
    int v = blockIdx.x * 4 + (threadIdx.x >> 6);
    if (v >= N) return;
    int l = threadIdx.x & 63;
    float2 acc = *(const float2*)(agg + (size_t)v * D + 2 * l);
    int e0 = offs[v], e1 = offs[v + 1];
    for (int j = e0; j < e1; ++j) {
        int e = eperm[j];
        int s = esrc[e], r = etyp[e];
        uint u = ((const uint*)(h + ((size_t)r * N + s) * D))[l];
        acc.x += bf_lo(u);
        acc.y += bf_hi(u);
    }
    float2 xv = *(const float2*)(x + (size_t)v * D + 2 * l);
    float2 x2v = {xv.x + acc.x, xv.y + acc.y};
    *(float2*)(agg + (size_t)v * D + 2 * l) = x2v;
    float s = x2v.x + x2v.y, s2 = x2v.x * x2v.x + x2v.y * x2v.y;
    #pragma unroll
    for (int o = 32; o; o >>= 1) { s += __shfl_xor(s, o, 64); s2 += __shfl_xor(s2, o, 64); }
    float mu = s * (1.0f / D);
    float var = s2 * (1.0f / D) - mu * mu;
    float inv = rsqrtf(var + EPS);
    int t = ntp[v];
    float2 g = *(const float2*)(gamma + t * D + 2 * l);
    float2 b = *(const float2*)(beta + t * D + 2 * l);
    float a0 = fmaxf((x2v.x - mu) * inv * g.x + b.x, 0.0f);
    float a1 = fmaxf((x2v.y - mu) * inv * g.y + b.y, 0.0f);
    ((uint*)(y2 + (size_t)v * D))[l] = ((uint)f2bf(a1) << 16) | f2bf(a0);
}

// ---------- node-type bucketing (64-aligned) ----------------------------------
// small layout (ints): [0..3] thist, [4..7] cursor4, [8..12] start[5], [16..] tob
__global__ void k_nhist(const int* __restrict__ ntp, int* __restrict__ small, int N) {
    __shared__ int c[4];
    if (threadIdx.x < 4) c[threadIdx.x] = 0;
    __syncthreads();
    int n = blockIdx.x * blockDim.x + threadIdx.x;
    if (n < N) atomicAdd(&c[ntp[n]], 1);
    __syncthreads();
    if (threadIdx.x < 4 && c[threadIdx.x]) atomicAdd(&small[threadIdx.x], c[threadIdx.x]);
}
__global__ void k_prep(int* __restrict__ small, int gridMlp) {
    __shared__ int st[5];
    if (threadIdx.x == 0) {
        int o = 0;
        for (int t = 0; t < 4; ++t) {
            small[8 + t] = o;
            st[t] = o;
            int pad = (small[t] + 63) & ~63;
            o += pad;
        }
        small[12] = o;
        st[4] = o;
    }
    __syncthreads();
    int* tob = small + 16;
    for (int b = threadIdx.x; b < gridMlp; b += blockDim.x) {
        int b64 = b * 64;
        int t = -1;
        for (int i = 0; i < 4; ++i)
            if (b64 >= st[i] && b64 < st[i + 1]) t = i;
        tob[b] = t;
    }
}
// R3 fix: block-aggregated ranks — 4 global atomics per BLOCK, not 1 per thread.
__global__ void k_nscatter(const int* __restrict__ ntp, int* __restrict__ small,
                           int* __restrict__ perm_pad, int N) {
    __shared__ int cnt[4], base[4];
    int tid = threadIdx.x;
    if (tid < 4) cnt[tid] = 0;
    __syncthreads();
    int n = blockIdx.x * blockDim.x + tid;
    int t = 0, rank = 0;
    bool valid = (n < N);
    if (valid) { t = ntp[n]; rank = atomicAdd(&cnt[t], 1); }  // LDS atomic
    __syncthreads();
    if (tid < 4) base[tid] = cnt[tid] ? atomicAdd(&small[4 + tid], cnt[tid]) : 0;
    __syncthreads();
    if (valid) perm_pad[small[8 + t] + base[t] + rank] = n;
}

// ---------- K5: MLP MFMA + residual + bias, type-uniform 64-row blocks --------
__global__ void k_mlp(const ushort* __restrict__ y2, const float* __restrict__ x2,
                      const int* __restrict__ perm_pad, const int* __restrict__ small,
                      const ushort* __restrict__ Wt, const float* __restrict__ bmlp,
                      float* __restrict__ out, int N) {
    int t = small[16 + blockIdx.x];
    if (t < 0) return;
    int wave = threadIdx.x >> 6;
    int lane = threadIdx.x & 63;
    int quad = lane >> 4;
    int base = blockIdx.x * 64 + wave * 16;
    int node = perm_pad[base + (lane & 15)];
    int arow = node < 0 ? 0 : node;
    short8 a[4];
    const ushort* yrow = y2 + (size_t)arow * D + quad * 8;
    #pragma unroll
    for (int ks = 0; ks < 4; ++ks) a[ks] = *(const short8*)(yrow + ks * 32);
    int srow[4];
    #pragma unroll
    for (int r = 0; r < 4; ++r) srow[r] = perm_pad[base + quad * 4 + r];
    const ushort* Wb = Wt + (size_t)(9 + t) * D * D;
    #pragma unroll
    for (int nt = 0; nt < 8; ++nt) {
        int n0 = nt * 16;
        float4v acc = {0.f, 0.f, 0.f, 0.f};
        const ushort* wrow = Wb + (size_t)(n0 + (lane & 15)) * D + quad * 8;
        #pragma unroll
        for (int ks = 0; ks < 4; ++ks) {
            short8 b = *(const short8*)(wrow + ks * 32);
            acc = __builtin_amdgcn_mfma_f32_16x16x32_bf16(a[ks], b, acc, 0, 0, 0);
        }
        int col = n0 + (lane & 15);
        float bm = bmlp[t * D + col];
        #pragma unroll
        for (int r = 0; r < 4; ++r) {
            if (srow[r] >= 0)
                out[(size_t)srow[r] * D + col] =
                    x2[(size_t)srow[r] * D + col] + acc[r] + bm;
        }
    }
}

// ---------- launch ------------------------------------------------------------
extern "C" void kernel_launch(void* const* d_in, const int* in_sizes, int n_in,
                              void* d_out, int out_size, void* d_ws, size_t ws_size,
                              hipStream_t stream) {
    const float* x          = (const float*)d_in[0];
    const int*   esrc       = (const int*)d_in[1];
    const int*   edst       = (const int*)d_in[2];
    const int*   ntyp       = (const int*)d_in[3];
    const int*   etyp       = (const int*)d_in[4];
    const float* conv_gamma = (const float*)d_in[5];
    const float* conv_beta  = (const float*)d_in[6];
    const float* W_rel      = (const float*)d_in[7];
    const float* W_root     = (const float*)d_in[8];
    const float* mlp_gamma  = (const float*)d_in[9];
    const float* mlp_beta   = (const float*)d_in[10];
    const float* W_mlp      = (const float*)d_in[11];
    const float* b_mlp      = (const float*)d_in[12];
    float* out = (float*)d_out;

    int N = in_sizes[0] / D;
    int E = in_sizes[1];
    int gridMlp = (N + 252 + 63) / 64;

    char* p = (char*)d_ws;
    auto take = [&p](size_t bytes) { char* q = p; p += (bytes + 255) & ~(size_t)255; return q; };
    ushort* y       = (ushort*)take((size_t)N * D * 2);
    ushort* y2      = (ushort*)take((size_t)N * D * 2);
    ushort* h       = (ushort*)take((size_t)8 * N * D * 2);
    float*  agg     = (float*)take((size_t)N * D * 4);
    ushort* Wt      = (ushort*)take((size_t)13 * D * D * 2);
    int*    hist    = (int*)take((size_t)N * 4);
    int*    offs    = (int*)take((size_t)(N + 1) * 4);
    int*    cursor  = (int*)take((size_t)N * 4);
    int*    eperm   = (int*)take((size_t)E * 4);
    int*    permpad = (int*)take((size_t)(N + 256) * 4);
    int*    small   = (int*)take((size_t)(16 + gridMlp) * 4);

    hipMemsetAsync(hist, 0, (size_t)N * 4, stream);
    hipMemsetAsync(small, 0, 16 * 4, stream);
    hipMemsetAsync(permpad, 0xFF, (size_t)(N + 256) * 4, stream);

    k_ln1<<<(N + 3) / 4, 256, 0, stream>>>(x, ntyp, conv_gamma, conv_beta, y, N);
    k_cvt<<<13, 256, 0, stream>>>(W_rel, W_root, W_mlp, Wt);

    k_ehist<<<(E + 255) / 256, 256, 0, stream>>>(edst, hist, E);
    k_scan<<<1, 1024, 0, stream>>>(hist, offs, cursor, N);
    k_escatter<<<(E + 255) / 256, 256, 0, stream>>>(edst, cursor, eperm, E);

    k_nhist<<<(N + 255) / 256, 256, 0, stream>>>(ntyp, small, N);
    k_prep<<<1, 256, 0, stream>>>(small, gridMlp);
    k_nscatter<<<(N + 255) / 256, 256, 0, stream>>>(ntyp, small, permpad, N);

    dim3 g2((N + 63) / 64, 9);
    k_gemm<<<g2, 256, 0, stream>>>(y, Wt, h, agg, N);

    k_edge_ln<<<(N + 3) / 4, 256, 0, stream>>>(h, x, agg, offs, eperm, esrc, etyp,
                                               ntyp, mlp_gamma, mlp_beta, y2, N);

    k_mlp<<<gridMlp, 256, 0, stream>>>(y2, agg, permpad, small, Wt, b_mlp, out, N);
}

// Round 4
// 400.307 us; speedup vs baseline: 3.3533x; 1.5343x over previous
//
#include <hip/hip_runtime.h>
#include <hip/hip_bf16.h>

#define D 128
#define EPS 1e-5f

typedef __attribute__((ext_vector_type(8))) short short8;
typedef __attribute__((ext_vector_type(4))) float float4v;

__device__ inline ushort f2bf(float f) {
    __hip_bfloat16 b = __float2bfloat16(f);
    return *reinterpret_cast<ushort*>(&b);
}
__device__ inline float bf_lo(uint u) { return __uint_as_float(u << 16); }
__device__ inline float bf_hi(uint u) { return __uint_as_float(u & 0xffff0000u); }

// ---------- K1: LN1 + ReLU, fp32 in -> bf16 out. One wave per node. ----------
__global__ void k_ln1(const float* __restrict__ x, const int* __restrict__ ntp,
                      const float* __restrict__ gamma, const float* __restrict__ beta,
                      ushort* __restrict__ y, int N) {
    int n = blockIdx.x * 4 + (threadIdx.x >> 6);
    if (n >= N) return;
    int l = threadIdx.x & 63;
    float2 v = *(const float2*)(x + (size_t)n * D + 2 * l);
    float s = v.x + v.y, s2 = v.x * v.x + v.y * v.y;
    #pragma unroll
    for (int o = 32; o; o >>= 1) { s += __shfl_xor(s, o, 64); s2 += __shfl_xor(s2, o, 64); }
    float mu = s * (1.0f / D);
    float var = s2 * (1.0f / D) - mu * mu;
    float inv = rsqrtf(var + EPS);
    int t = ntp[n];
    float2 g = *(const float2*)(gamma + t * D + 2 * l);
    float2 b = *(const float2*)(beta + t * D + 2 * l);
    float a0 = fmaxf((v.x - mu) * inv * g.x + b.x, 0.0f);
    float a1 = fmaxf((v.y - mu) * inv * g.y + b.y, 0.0f);
    ((uint*)(y + (size_t)n * D))[l] = ((uint)f2bf(a1) << 16) | f2bf(a0);
}

// ---------- K2: 13 weights -> bf16 transposed Wt[m][n][k] ---------------------
// m==0: W_root, m 1..8: W_rel[m-1], m 9..12: W_mlp[m-9]
__global__ void k_cvt(const float* __restrict__ Wrel, const float* __restrict__ Wroot,
                      const float* __restrict__ Wmlp, ushort* __restrict__ Wt) {
    __shared__ ushort t[128][136];
    int m = blockIdx.x;
    const float* src = (m == 0) ? Wroot
                     : (m <= 8) ? Wrel + (size_t)(m - 1) * D * D
                                : Wmlp + (size_t)(m - 9) * D * D;
    for (int i = threadIdx.x; i < D * D; i += 256) {
        int k = i >> 7, n = i & 127;
        t[n][k] = f2bf(src[i]);
    }
    __syncthreads();
    ushort* dst = Wt + (size_t)m * D * D;
    for (int i = threadIdx.x; i < D * D; i += 256) dst[i] = t[i >> 7][i & 127];
}

// ---------- edge bucketing by dst: hist, 2-level scan, scatter ----------------
__global__ void k_ehist(const int* __restrict__ edst, int* __restrict__ hist, int E) {
    int e = blockIdx.x * blockDim.x + threadIdx.x;
    if (e < E) atomicAdd(&hist[edst[e]], 1);
}
// scan1: per-block (1024 entries) sum -> blocksum[b]
__global__ void k_scan1(const int* __restrict__ hist, int* __restrict__ blocksum, int N) {
    __shared__ int ps[256];
    int t = threadIdx.x;
    int base = blockIdx.x * 1024 + t * 4;
    int s = 0;
    #pragma unroll
    for (int k = 0; k < 4; ++k) { int i = base + k; if (i < N) s += hist[i]; }
    ps[t] = s;
    __syncthreads();
    if (t == 0) {
        int tot = 0;
        for (int i = 0; i < 256; ++i) tot += ps[i];
        blocksum[blockIdx.x] = tot;
    }
}
// scan2: serial exclusive scan of B blocksums; writes offs[N] = total
__global__ void k_scan2(int* __restrict__ blocksum, int* __restrict__ offs, int B, int N) {
    if (threadIdx.x == 0) {
        int o = 0;
        for (int b = 0; b < B; ++b) { int c = blocksum[b]; blocksum[b] = o; o += c; }
        offs[N] = o;
    }
}
// scan3: per-block local scan + blockoff -> offs/cursor
__global__ void k_scan3(const int* __restrict__ hist, const int* __restrict__ blockoff,
                        int* __restrict__ offs, int* __restrict__ cursor, int N) {
    __shared__ int ps[256];
    int t = threadIdx.x;
    int base = blockIdx.x * 1024 + t * 4;
    int s = 0;
    #pragma unroll
    for (int k = 0; k < 4; ++k) { int i = base + k; if (i < N) s += hist[i]; }
    int mysum = s;
    ps[t] = s;
    __syncthreads();
    for (int off = 1; off < 256; off <<= 1) {
        int v = (t >= off) ? ps[t - off] : 0;
        __syncthreads();
        ps[t] += v;
        __syncthreads();
    }
    int run = ps[t] - mysum + blockoff[blockIdx.x];
    #pragma unroll
    for (int k = 0; k < 4; ++k) {
        int i = base + k;
        if (i < N) { offs[i] = run; cursor[i] = run; run += hist[i]; }
    }
}
// scatter: epack[pos] = (etyp << 28) | esrc, sorted by dst
__global__ void k_escatter(const int* __restrict__ edst, const int* __restrict__ esrc,
                           const int* __restrict__ etyp, int* __restrict__ cursor,
                           uint* __restrict__ epack, int E) {
    int e = blockIdx.x * blockDim.x + threadIdx.x;
    if (e < E) {
        int p = atomicAdd(&cursor[edst[e]], 1);
        epack[p] = ((uint)etyp[e] << 28) | (uint)esrc[e];
    }
}

// ---------- K3: z[v][r] = sum of y[src] over edges (dst=v, type=r) ------------
// one wave per dst; per-wave LDS accumulators [8 relations][64 lanes] float2
__global__ void k_zagg(const ushort* __restrict__ ybuf, const int* __restrict__ offs,
                       const uint* __restrict__ epack, ushort* __restrict__ zbuf, int N) {
    __shared__ float2 zacc[4][8][64];
    int wave = threadIdx.x >> 6;
    int l = threadIdx.x & 63;
    int v = blockIdx.x * 4 + wave;
    if (v >= N) return;
    #pragma unroll
    for (int r = 0; r < 8; ++r) zacc[wave][r][l] = make_float2(0.f, 0.f);
    const uint* yb = (const uint*)ybuf;
    int j = offs[v], e1 = offs[v + 1];
    for (; j + 1 < e1; j += 2) {
        uint p0 = epack[j], p1 = epack[j + 1];
        uint u0 = yb[(size_t)(p0 & 0x0FFFFFFFu) * 64 + l];
        uint u1 = yb[(size_t)(p1 & 0x0FFFFFFFu) * 64 + l];
        float2* a0 = &zacc[wave][p0 >> 28][l];
        a0->x += bf_lo(u0); a0->y += bf_hi(u0);
        float2* a1 = &zacc[wave][p1 >> 28][l];
        a1->x += bf_lo(u1); a1->y += bf_hi(u1);
    }
    if (j < e1) {
        uint p0 = epack[j];
        uint u0 = yb[(size_t)(p0 & 0x0FFFFFFFu) * 64 + l];
        float2* a0 = &zacc[wave][p0 >> 28][l];
        a0->x += bf_lo(u0); a0->y += bf_hi(u0);
    }
    uint* zrow = (uint*)(zbuf + (size_t)v * 1024);
    #pragma unroll
    for (int r = 0; r < 8; ++r) {
        float2 a = zacc[wave][r][l];
        zrow[r * 64 + l] = ((uint)f2bf(a.y) << 16) | f2bf(a.x);
    }
}

// ---------- K4: agg = [y|z] @ [Wroot;Wrel] (K=1152) + x, fused LN2+ReLU -------
// grid ceil(N/128), block 256; wave = 32 rows (2x16) x 128 cols.
__launch_bounds__(256)
__global__ void k_gemm2(const ushort* __restrict__ ybuf, const ushort* __restrict__ zbuf,
                        const ushort* __restrict__ Wt, const float* __restrict__ x,
                        const int* __restrict__ ntp,
                        const float* __restrict__ gamma, const float* __restrict__ beta,
                        float* __restrict__ x2, ushort* __restrict__ y2, int N) {
    int wave = threadIdx.x >> 6;
    int lane = threadIdx.x & 63;
    int quad = lane >> 4;
    int l15 = lane & 15;
    int base = blockIdx.x * 128 + wave * 32;

    float4v acc[2][8];
    #pragma unroll
    for (int h = 0; h < 2; ++h)
        #pragma unroll
        for (int nt = 0; nt < 8; ++nt) acc[h][nt] = (float4v){0.f, 0.f, 0.f, 0.f};

    for (int mat = 0; mat < 9; ++mat) {
        short8 a[2][4];
        #pragma unroll
        for (int h = 0; h < 2; ++h) {
            int row = base + h * 16 + l15;
            int rc = min(row, N - 1);
            const ushort* ap = (mat == 0)
                ? ybuf + (size_t)rc * 128 + quad * 8
                : zbuf + (size_t)rc * 1024 + (mat - 1) * 128 + quad * 8;
            #pragma unroll
            for (int ks = 0; ks < 4; ++ks) a[h][ks] = *(const short8*)(ap + ks * 32);
        }
        const ushort* Wb = Wt + (size_t)mat * D * D;
        #pragma unroll
        for (int nt = 0; nt < 8; ++nt) {
            const ushort* wrow = Wb + (size_t)(nt * 16 + l15) * D + quad * 8;
            #pragma unroll
            for (int ks = 0; ks < 4; ++ks) {
                short8 b = *(const short8*)(wrow + ks * 32);
                acc[0][nt] = __builtin_amdgcn_mfma_f32_16x16x32_bf16(a[0][ks], b, acc[0][nt], 0, 0, 0);
                acc[1][nt] = __builtin_amdgcn_mfma_f32_16x16x32_bf16(a[1][ks], b, acc[1][nt], 0, 0, 0);
            }
        }
    }

    // epilogue: x2 = x + acc; LN2 + ReLU -> y2
    #pragma unroll
    for (int h = 0; h < 2; ++h) {
        float s[4] = {0.f, 0.f, 0.f, 0.f}, s2[4] = {0.f, 0.f, 0.f, 0.f};
        #pragma unroll
        for (int nt = 0; nt < 8; ++nt) {
            int col = nt * 16 + l15;
            #pragma unroll
            for (int r = 0; r < 4; ++r) {
                int row = base + h * 16 + quad * 4 + r;
                float xv = (row < N) ? x[(size_t)row * D + col] : 0.f;
                float t = acc[h][nt][r] + xv;
                acc[h][nt][r] = t;
                s[r] += t; s2[r] += t * t;
            }
        }
        #pragma unroll
        for (int r = 0; r < 4; ++r) {
            #pragma unroll
            for (int o = 1; o < 16; o <<= 1) {
                s[r]  += __shfl_xor(s[r],  o, 64);
                s2[r] += __shfl_xor(s2[r], o, 64);
            }
        }
        #pragma unroll
        for (int r = 0; r < 4; ++r) {
            int row = base + h * 16 + quad * 4 + r;
            int rc = min(row, N - 1);
            int t = ntp[rc];
            float mu  = s[r] * (1.0f / D);
            float var = s2[r] * (1.0f / D) - mu * mu;
            float inv = rsqrtf(var + EPS);
            #pragma unroll
            for (int nt = 0; nt < 8; ++nt) {
                int col = nt * 16 + l15;
                float xx = acc[h][nt][r];
                float yn = fmaxf((xx - mu) * inv * gamma[t * D + col] + beta[t * D + col], 0.f);
                if (row < N) {
                    x2[(size_t)row * D + col] = xx;
                    y2[(size_t)row * D + col] = f2bf(yn);
                }
            }
        }
    }
}

// ---------- node-type bucketing (64-aligned) ----------------------------------
__global__ void k_nhist(const int* __restrict__ ntp, int* __restrict__ small, int N) {
    __shared__ int c[4];
    if (threadIdx.x < 4) c[threadIdx.x] = 0;
    __syncthreads();
    int n = blockIdx.x * blockDim.x + threadIdx.x;
    if (n < N) atomicAdd(&c[ntp[n]], 1);
    __syncthreads();
    if (threadIdx.x < 4 && c[threadIdx.x]) atomicAdd(&small[threadIdx.x], c[threadIdx.x]);
}
__global__ void k_prep(int* __restrict__ small, int gridMlp) {
    __shared__ int st[5];
    if (threadIdx.x == 0) {
        int o = 0;
        for (int t = 0; t < 4; ++t) {
            small[8 + t] = o;
            st[t] = o;
            o += (small[t] + 63) & ~63;
        }
        small[12] = o;
        st[4] = o;
    }
    __syncthreads();
    int* tob = small + 16;
    for (int b = threadIdx.x; b < gridMlp; b += blockDim.x) {
        int b64 = b * 64;
        int t = -1;
        for (int i = 0; i < 4; ++i)
            if (b64 >= st[i] && b64 < st[i + 1]) t = i;
        tob[b] = t;
    }
}
__global__ void k_nscatter(const int* __restrict__ ntp, int* __restrict__ small,
                           int* __restrict__ perm_pad, int N) {
    __shared__ int cnt[4], base[4];
    int tid = threadIdx.x;
    if (tid < 4) cnt[tid] = 0;
    __syncthreads();
    int n = blockIdx.x * blockDim.x + tid;
    int t = 0, rank = 0;
    bool valid = (n < N);
    if (valid) { t = ntp[n]; rank = atomicAdd(&cnt[t], 1); }
    __syncthreads();
    if (tid < 4) base[tid] = cnt[tid] ? atomicAdd(&small[4 + tid], cnt[tid]) : 0;
    __syncthreads();
    if (valid) perm_pad[small[8 + t] + base[t] + rank] = n;
}

// ---------- K5: MLP MFMA + residual + bias, type-uniform 64-row blocks --------
__global__ void k_mlp(const ushort* __restrict__ y2, const float* __restrict__ x2,
                      const int* __restrict__ perm_pad, const int* __restrict__ small,
                      const ushort* __restrict__ Wt, const float* __restrict__ bmlp,
                      float* __restrict__ out, int N) {
    int t = small[16 + blockIdx.x];
    if (t < 0) return;
    int wave = threadIdx.x >> 6;
    int lane = threadIdx.x & 63;
    int quad = lane >> 4;
    int base = blockIdx.x * 64 + wave * 16;
    int node = perm_pad[base + (lane & 15)];
    int arow = node < 0 ? 0 : node;
    short8 a[4];
    const ushort* yrow = y2 + (size_t)arow * D + quad * 8;
    #pragma unroll
    for (int ks = 0; ks < 4; ++ks) a[ks] = *(const short8*)(yrow + ks * 32);
    int srow[4];
    #pragma unroll
    for (int r = 0; r < 4; ++r) srow[r] = perm_pad[base + quad * 4 + r];
    const ushort* Wb = Wt + (size_t)(9 + t) * D * D;
    #pragma unroll
    for (int nt = 0; nt < 8; ++nt) {
        int n0 = nt * 16;
        float4v acc = {0.f, 0.f, 0.f, 0.f};
        const ushort* wrow = Wb + (size_t)(n0 + (lane & 15)) * D + quad * 8;
        #pragma unroll
        for (int ks = 0; ks < 4; ++ks) {
            short8 b = *(const short8*)(wrow + ks * 32);
            acc = __builtin_amdgcn_mfma_f32_16x16x32_bf16(a[ks], b, acc, 0, 0, 0);
        }
        int col = n0 + (lane & 15);
        float bm = bmlp[t * D + col];
        #pragma unroll
        for (int r = 0; r < 4; ++r) {
            if (srow[r] >= 0)
                out[(size_t)srow[r] * D + col] =
                    x2[(size_t)srow[r] * D + col] + acc[r] + bm;
        }
    }
}

// ---------- launch ------------------------------------------------------------
extern "C" void kernel_launch(void* const* d_in, const int* in_sizes, int n_in,
                              void* d_out, int out_size, void* d_ws, size_t ws_size,
                              hipStream_t stream) {
    const float* x          = (const float*)d_in[0];
    const int*   esrc       = (const int*)d_in[1];
    const int*   edst       = (const int*)d_in[2];
    const int*   ntyp       = (const int*)d_in[3];
    const int*   etyp       = (const int*)d_in[4];
    const float* conv_gamma = (const float*)d_in[5];
    const float* conv_beta  = (const float*)d_in[6];
    const float* W_rel      = (const float*)d_in[7];
    const float* W_root     = (const float*)d_in[8];
    const float* mlp_gamma  = (const float*)d_in[9];
    const float* mlp_beta   = (const float*)d_in[10];
    const float* W_mlp      = (const float*)d_in[11];
    const float* b_mlp      = (const float*)d_in[12];
    float* out = (float*)d_out;

    int N = in_sizes[0] / D;
    int E = in_sizes[1];
    int gridMlp = (N + 252 + 63) / 64;
    int scanB = (N + 1023) / 1024;

    char* p = (char*)d_ws;
    auto take = [&p](size_t bytes) { char* q = p; p += (bytes + 255) & ~(size_t)255; return q; };
    ushort* ybuf   = (ushort*)take((size_t)N * D * 2);
    ushort* y2     = (ushort*)take((size_t)N * D * 2);
    ushort* zbuf   = (ushort*)take((size_t)N * 1024 * 2);
    float*  x2     = (float*)take((size_t)N * D * 4);
    ushort* Wt     = (ushort*)take((size_t)13 * D * D * 2);
    int*    hist   = (int*)take((size_t)N * 4);
    int*    offs   = (int*)take((size_t)(N + 1) * 4);
    int*    cursor = (int*)take((size_t)N * 4);
    uint*   epack  = (uint*)take((size_t)E * 4);
    int*    permpad= (int*)take((size_t)(N + 256) * 4);
    int*    small  = (int*)take((size_t)(16 + gridMlp) * 4);
    int*    bsum   = (int*)take((size_t)scanB * 4);

    hipMemsetAsync(hist, 0, (size_t)N * 4, stream);
    hipMemsetAsync(small, 0, 16 * 4, stream);
    hipMemsetAsync(permpad, 0xFF, (size_t)(N + 256) * 4, stream);

    k_ln1<<<(N + 3) / 4, 256, 0, stream>>>(x, ntyp, conv_gamma, conv_beta, ybuf, N);
    k_cvt<<<13, 256, 0, stream>>>(W_rel, W_root, W_mlp, Wt);

    k_ehist<<<(E + 255) / 256, 256, 0, stream>>>(edst, hist, E);
    k_scan1<<<scanB, 256, 0, stream>>>(hist, bsum, N);
    k_scan2<<<1, 64, 0, stream>>>(bsum, offs, scanB, N);
    k_scan3<<<scanB, 256, 0, stream>>>(hist, bsum, offs, cursor, N);
    k_escatter<<<(E + 255) / 256, 256, 0, stream>>>(edst, esrc, etyp, cursor, epack, E);

    k_nhist<<<(N + 255) / 256, 256, 0, stream>>>(ntyp, small, N);
    k_prep<<<1, 256, 0, stream>>>(small, gridMlp);
    k_nscatter<<<(N + 255) / 256, 256, 0, stream>>>(ntyp, small, permpad, N);

    k_zagg<<<(N + 3) / 4, 256, 0, stream>>>(ybuf, offs, epack, zbuf, N);

    k_gemm2<<<(N + 127) / 128, 256, 0, stream>>>(ybuf, zbuf, Wt, x, ntyp,
                                                 mlp_gamma, mlp_beta, x2, y2, N);

    k_mlp<<<gridMlp, 256, 0, stream>>>(y2, x2, permpad, small, Wt, b_mlp, out, N);
}

// Round 5
// 360.472 us; speedup vs baseline: 3.7239x; 1.1105x over previous
//
#include <hip/hip_runtime.h>
#include <hip/hip_bf16.h>

#define D 128
#define EPS 1e-5f

typedef __attribute__((ext_vector_type(8))) short short8;
typedef __attribute__((ext_vector_type(4))) float float4v;

__device__ inline ushort f2bf(float f) {
    __hip_bfloat16 b = __float2bfloat16(f);
    return *reinterpret_cast<ushort*>(&b);
}
__device__ inline float bf_lo(uint u) { return __uint_as_float(u << 16); }
__device__ inline float bf_hi(uint u) { return __uint_as_float(u & 0xffff0000u); }

// ---------- K1: LN1 + ReLU, fp32 in -> bf16 out. One wave per node. ----------
__global__ void k_ln1(const float* __restrict__ x, const int* __restrict__ ntp,
                      const float* __restrict__ gamma, const float* __restrict__ beta,
                      ushort* __restrict__ y, int N) {
    int n = blockIdx.x * 4 + (threadIdx.x >> 6);
    if (n >= N) return;
    int l = threadIdx.x & 63;
    float2 v = *(const float2*)(x + (size_t)n * D + 2 * l);
    float s = v.x + v.y, s2 = v.x * v.x + v.y * v.y;
    #pragma unroll
    for (int o = 32; o; o >>= 1) { s += __shfl_xor(s, o, 64); s2 += __shfl_xor(s2, o, 64); }
    float mu = s * (1.0f / D);
    float var = s2 * (1.0f / D) - mu * mu;
    float inv = rsqrtf(var + EPS);
    int t = ntp[n];
    float2 g = *(const float2*)(gamma + t * D + 2 * l);
    float2 b = *(const float2*)(beta + t * D + 2 * l);
    float a0 = fmaxf((v.x - mu) * inv * g.x + b.x, 0.0f);
    float a1 = fmaxf((v.y - mu) * inv * g.y + b.y, 0.0f);
    ((uint*)(y + (size_t)n * D))[l] = ((uint)f2bf(a1) << 16) | f2bf(a0);
}

// ---------- K2: weights -> bf16 in MFMA B-FRAGMENT order ----------------------
// m==0: W_root, 1..8: W_rel[m-1], 9..12: W_mlp[m-9].
// Fragment order: idx = ((nt*4+ks)*64 + lane)*8 + j holds
//   W[k = ks*32 + (lane>>4)*8 + j][n = nt*16 + (lane&15)]
// so a wave's short8 b-read at (nt,ks) is 64 lanes x 16B contiguous.
__global__ void k_cvt(const float* __restrict__ Wrel, const float* __restrict__ Wroot,
                      const float* __restrict__ Wmlp, ushort* __restrict__ Wt) {
    __shared__ ushort t[128][136];
    int m = blockIdx.x;
    const float* src = (m == 0) ? Wroot
                     : (m <= 8) ? Wrel + (size_t)(m - 1) * D * D
                                : Wmlp + (size_t)(m - 9) * D * D;
    for (int i = threadIdx.x; i < D * D; i += 256) {
        int k = i >> 7, n = i & 127;
        t[n][k] = f2bf(src[i]);
    }
    __syncthreads();
    ushort* dst = Wt + (size_t)m * D * D;
    for (int i = threadIdx.x; i < D * D; i += 256) {
        int frag = i >> 9;            // 0..31  (nt*4+ks)
        int lane = (i >> 3) & 63;
        int j = i & 7;
        int nt = frag >> 2, ks = frag & 3;
        int n = nt * 16 + (lane & 15);
        int k = ks * 32 + (lane >> 4) * 8 + j;
        dst[i] = t[n][k];
    }
}

// ---------- edge bucketing by dst: hist, 2-level scan, scatter ----------------
__global__ void k_ehist(const int* __restrict__ edst, int* __restrict__ hist, int E) {
    int e = blockIdx.x * blockDim.x + threadIdx.x;
    if (e < E) atomicAdd(&hist[edst[e]], 1);
}
__global__ void k_scan1(const int* __restrict__ hist, int* __restrict__ blocksum, int N) {
    __shared__ int ps[256];
    int t = threadIdx.x;
    int base = blockIdx.x * 1024 + t * 4;
    int s = 0;
    #pragma unroll
    for (int k = 0; k < 4; ++k) { int i = base + k; if (i < N) s += hist[i]; }
    ps[t] = s;
    __syncthreads();
    if (t == 0) {
        int tot = 0;
        for (int i = 0; i < 256; ++i) tot += ps[i];
        blocksum[blockIdx.x] = tot;
    }
}
__global__ void k_scan2(int* __restrict__ blocksum, int* __restrict__ offs, int B, int N) {
    if (threadIdx.x == 0) {
        int o = 0;
        for (int b = 0; b < B; ++b) { int c = blocksum[b]; blocksum[b] = o; o += c; }
        offs[N] = o;
    }
}
__global__ void k_scan3(const int* __restrict__ hist, const int* __restrict__ blockoff,
                        int* __restrict__ offs, int* __restrict__ cursor, int N) {
    __shared__ int ps[256];
    int t = threadIdx.x;
    int base = blockIdx.x * 1024 + t * 4;
    int s = 0;
    #pragma unroll
    for (int k = 0; k < 4; ++k) { int i = base + k; if (i < N) s += hist[i]; }
    int mysum = s;
    ps[t] = s;
    __syncthreads();
    for (int off = 1; off < 256; off <<= 1) {
        int v = (t >= off) ? ps[t - off] : 0;
        __syncthreads();
        ps[t] += v;
        __syncthreads();
    }
    int run = ps[t] - mysum + blockoff[blockIdx.x];
    #pragma unroll
    for (int k = 0; k < 4; ++k) {
        int i = base + k;
        if (i < N) { offs[i] = run; cursor[i] = run; run += hist[i]; }
    }
}
__global__ void k_escatter(const int* __restrict__ edst, const int* __restrict__ esrc,
                           const int* __restrict__ etyp, int* __restrict__ cursor,
                           uint* __restrict__ epack, int E) {
    int e = blockIdx.x * blockDim.x + threadIdx.x;
    if (e < E) {
        int p = atomicAdd(&cursor[edst[e]], 1);
        epack[p] = ((uint)etyp[e] << 28) | (uint)esrc[e];
    }
}

// ---------- K3: z[v][r] = sum of y[src] over edges (dst=v, type=r) ------------
// one wave per dst; 8 register float2 accumulators, wave-uniform switch on type;
// epack batch-loaded 64-wide and broadcast via shfl.
__global__ void k_zagg(const ushort* __restrict__ ybuf, const int* __restrict__ offs,
                       const uint* __restrict__ epack, ushort* __restrict__ zbuf, int N) {
    int wave = threadIdx.x >> 6;
    int l = threadIdx.x & 63;
    int v = blockIdx.x * 4 + wave;
    if (v >= N) return;
    float2 a0 = {0.f,0.f}, a1 = {0.f,0.f}, a2 = {0.f,0.f}, a3 = {0.f,0.f};
    float2 a4 = {0.f,0.f}, a5 = {0.f,0.f}, a6 = {0.f,0.f}, a7 = {0.f,0.f};
    const uint* yb = (const uint*)ybuf;
    int j = offs[v], e1 = offs[v + 1];
    while (j < e1) {
        int chunk = min(64, e1 - j);
        uint pl = (j + l < e1) ? epack[j + l] : 0;
        for (int i = 0; i < chunk; ++i) {
            uint p = __shfl(pl, i, 64);                 // wave-uniform
            uint u = yb[(size_t)(p & 0x0FFFFFFFu) * 64 + l];
            float lo = bf_lo(u), hi = bf_hi(u);
            switch (p >> 28) {                           // uniform branch
                case 0: a0.x += lo; a0.y += hi; break;
                case 1: a1.x += lo; a1.y += hi; break;
                case 2: a2.x += lo; a2.y += hi; break;
                case 3: a3.x += lo; a3.y += hi; break;
                case 4: a4.x += lo; a4.y += hi; break;
                case 5: a5.x += lo; a5.y += hi; break;
                case 6: a6.x += lo; a6.y += hi; break;
                default: a7.x += lo; a7.y += hi; break;
            }
        }
        j += chunk;
    }
    uint* zrow = (uint*)(zbuf + (size_t)v * 1024);
    zrow[0 * 64 + l] = ((uint)f2bf(a0.y) << 16) | f2bf(a0.x);
    zrow[1 * 64 + l] = ((uint)f2bf(a1.y) << 16) | f2bf(a1.x);
    zrow[2 * 64 + l] = ((uint)f2bf(a2.y) << 16) | f2bf(a2.x);
    zrow[3 * 64 + l] = ((uint)f2bf(a3.y) << 16) | f2bf(a3.x);
    zrow[4 * 64 + l] = ((uint)f2bf(a4.y) << 16) | f2bf(a4.x);
    zrow[5 * 64 + l] = ((uint)f2bf(a5.y) << 16) | f2bf(a5.x);
    zrow[6 * 64 + l] = ((uint)f2bf(a6.y) << 16) | f2bf(a6.x);
    zrow[7 * 64 + l] = ((uint)f2bf(a7.y) << 16) | f2bf(a7.x);
}

// ---------- K4: agg = [y|z] @ [Wroot;Wrel] (K=1152) + x, fused LN2+ReLU -------
// grid ceil(N/64), block 256 (4 waves x 16 rows). W-mat staged in LDS per mat,
// fragment-ordered (conflict-free ds_read_b128, lane-contiguous staging).
__launch_bounds__(256)
__global__ void k_gemm2(const ushort* __restrict__ ybuf, const ushort* __restrict__ zbuf,
                        const ushort* __restrict__ Wt, const float* __restrict__ x,
                        const int* __restrict__ ntp,
                        const float* __restrict__ gamma, const float* __restrict__ beta,
                        float* __restrict__ x2, ushort* __restrict__ y2, int N) {
    __shared__ ushort wsm[16384];                       // 32 KB
    int tid = threadIdx.x;
    int wave = tid >> 6, lane = tid & 63;
    int quad = lane >> 4, l15 = lane & 15;
    int base = blockIdx.x * 64 + wave * 16;
    int arow = min(base + l15, N - 1);
    const ushort* yrow = ybuf + (size_t)arow * 128;
    const ushort* zrow = zbuf + (size_t)arow * 1024;

    float4v acc[8];
    #pragma unroll
    for (int nt = 0; nt < 8; ++nt) acc[nt] = (float4v){0.f, 0.f, 0.f, 0.f};

    for (int mat = 0; mat < 9; ++mat) {
        __syncthreads();                                // protect wsm overwrite
        const ushort* wsrc = Wt + (size_t)mat * 16384;
        #pragma unroll
        for (int jj = 0; jj < 8; ++jj) {
            uint4 w = *(const uint4*)(wsrc + jj * 2048 + tid * 8);
            *(uint4*)(wsm + jj * 2048 + tid * 8) = w;
        }
        __syncthreads();
        const ushort* ap = (mat == 0) ? yrow : zrow + (mat - 1) * 128;
        short8 a[4];
        #pragma unroll
        for (int ks = 0; ks < 4; ++ks) a[ks] = *(const short8*)(ap + ks * 32 + quad * 8);
        #pragma unroll
        for (int nt = 0; nt < 8; ++nt) {
            #pragma unroll
            for (int ks = 0; ks < 4; ++ks) {
                short8 b = *(const short8*)(wsm + (((nt * 4 + ks) * 64 + lane) << 3));
                acc[nt] = __builtin_amdgcn_mfma_f32_16x16x32_bf16(a[ks], b, acc[nt], 0, 0, 0);
            }
        }
    }

    // epilogue: x2 = x + acc; LN2 + ReLU -> y2
    float s[4] = {0.f, 0.f, 0.f, 0.f}, s2[4] = {0.f, 0.f, 0.f, 0.f};
    #pragma unroll
    for (int nt = 0; nt < 8; ++nt) {
        int col = nt * 16 + l15;
        #pragma unroll
        for (int r = 0; r < 4; ++r) {
            int row = base + quad * 4 + r;
            float xv = (row < N) ? x[(size_t)row * D + col] : 0.f;
            float t = acc[nt][r] + xv;
            acc[nt][r] = t;
            s[r] += t; s2[r] += t * t;
        }
    }
    #pragma unroll
    for (int r = 0; r < 4; ++r) {
        #pragma unroll
        for (int o = 1; o < 16; o <<= 1) {
            s[r]  += __shfl_xor(s[r],  o, 64);
            s2[r] += __shfl_xor(s2[r], o, 64);
        }
    }
    #pragma unroll
    for (int r = 0; r < 4; ++r) {
        int row = base + quad * 4 + r;
        int rc = min(row, N - 1);
        int t = ntp[rc];
        float mu  = s[r] * (1.0f / D);
        float var = s2[r] * (1.0f / D) - mu * mu;
        float inv = rsqrtf(var + EPS);
        #pragma unroll
        for (int nt = 0; nt < 8; ++nt) {
            int col = nt * 16 + l15;
            float xx = acc[nt][r];
            float yn = fmaxf((xx - mu) * inv * gamma[t * D + col] + beta[t * D + col], 0.f);
            if (row < N) {
                x2[(size_t)row * D + col] = xx;
                y2[(size_t)row * D + col] = f2bf(yn);
            }
        }
    }
}

// ---------- node-type bucketing (64-aligned) ----------------------------------
__global__ void k_nhist(const int* __restrict__ ntp, int* __restrict__ small, int N) {
    __shared__ int c[4];
    if (threadIdx.x < 4) c[threadIdx.x] = 0;
    __syncthreads();
    int n = blockIdx.x * blockDim.x + threadIdx.x;
    if (n < N) atomicAdd(&c[ntp[n]], 1);
    __syncthreads();
    if (threadIdx.x < 4 && c[threadIdx.x]) atomicAdd(&small[threadIdx.x], c[threadIdx.x]);
}
__global__ void k_prep(int* __restrict__ small, int gridMlp) {
    __shared__ int st[5];
    if (threadIdx.x == 0) {
        int o = 0;
        for (int t = 0; t < 4; ++t) {
            small[8 + t] = o;
            st[t] = o;
            o += (small[t] + 63) & ~63;
        }
        small[12] = o;
        st[4] = o;
    }
    __syncthreads();
    int* tob = small + 16;
    for (int b = threadIdx.x; b < gridMlp; b += blockDim.x) {
        int b64 = b * 64;
        int t = -1;
        for (int i = 0; i < 4; ++i)
            if (b64 >= st[i] && b64 < st[i + 1]) t = i;
        tob[b] = t;
    }
}
__global__ void k_nscatter(const int* __restrict__ ntp, int* __restrict__ small,
                           int* __restrict__ perm_pad, int N) {
    __shared__ int cnt[4], base[4];
    int tid = threadIdx.x;
    if (tid < 4) cnt[tid] = 0;
    __syncthreads();
    int n = blockIdx.x * blockDim.x + tid;
    int t = 0, rank = 0;
    bool valid = (n < N);
    if (valid) { t = ntp[n]; rank = atomicAdd(&cnt[t], 1); }
    __syncthreads();
    if (tid < 4) base[tid] = cnt[tid] ? atomicAdd(&small[4 + tid], cnt[tid]) : 0;
    __syncthreads();
    if (valid) perm_pad[small[8 + t] + base[t] + rank] = n;
}

// ---------- K5: MLP MFMA + residual + bias, type-uniform 64-row blocks --------
__global__ void k_mlp(const ushort* __restrict__ y2, const float* __restrict__ x2,
                      const int* __restrict__ perm_pad, const int* __restrict__ small,
                      const ushort* __restrict__ Wt, const float* __restrict__ bmlp,
                      float* __restrict__ out, int N) {
    int t = small[16 + blockIdx.x];
    if (t < 0) return;
    int wave = threadIdx.x >> 6;
    int lane = threadIdx.x & 63;
    int quad = lane >> 4;
    int base = blockIdx.x * 64 + wave * 16;
    int node = perm_pad[base + (lane & 15)];
    int arow = node < 0 ? 0 : node;
    short8 a[4];
    const ushort* yrow = y2 + (size_t)arow * D + quad * 8;
    #pragma unroll
    for (int ks = 0; ks < 4; ++ks) a[ks] = *(const short8*)(yrow + ks * 32);
    int srow[4];
    #pragma unroll
    for (int r = 0; r < 4; ++r) srow[r] = perm_pad[base + quad * 4 + r];
    const ushort* Wb = Wt + (size_t)(9 + t) * D * D;
    #pragma unroll
    for (int nt = 0; nt < 8; ++nt) {
        float4v acc = {0.f, 0.f, 0.f, 0.f};
        #pragma unroll
        for (int ks = 0; ks < 4; ++ks) {
            short8 b = *(const short8*)(Wb + (((nt * 4 + ks) * 64 + lane) << 3));
            acc = __builtin_amdgcn_mfma_f32_16x16x32_bf16(a[ks], b, acc, 0, 0, 0);
        }
        int col = nt * 16 + (lane & 15);
        float bm = bmlp[t * D + col];
        #pragma unroll
        for (int r = 0; r < 4; ++r) {
            if (srow[r] >= 0)
                out[(size_t)srow[r] * D + col] =
                    x2[(size_t)srow[r] * D + col] + acc[r] + bm;
        }
    }
}

// ---------- launch ------------------------------------------------------------
extern "C" void kernel_launch(void* const* d_in, const int* in_sizes, int n_in,
                              void* d_out, int out_size, void* d_ws, size_t ws_size,
                              hipStream_t stream) {
    const float* x          = (const float*)d_in[0];
    const int*   esrc       = (const int*)d_in[1];
    const int*   edst       = (const int*)d_in[2];
    const int*   ntyp       = (const int*)d_in[3];
    const int*   etyp       = (const int*)d_in[4];
    const float* conv_gamma = (const float*)d_in[5];
    const float* conv_beta  = (const float*)d_in[6];
    const float* W_rel      = (const float*)d_in[7];
    const float* W_root     = (const float*)d_in[8];
    const float* mlp_gamma  = (const float*)d_in[9];
    const float* mlp_beta   = (const float*)d_in[10];
    const float* W_mlp      = (const float*)d_in[11];
    const float* b_mlp      = (const float*)d_in[12];
    float* out = (float*)d_out;

    int N = in_sizes[0] / D;
    int E = in_sizes[1];
    int gridMlp = (N + 252 + 63) / 64;
    int scanB = (N + 1023) / 1024;

    char* p = (char*)d_ws;
    auto take = [&p](size_t bytes) { char* q = p; p += (bytes + 255) & ~(size_t)255; return q; };
    ushort* ybuf   = (ushort*)take((size_t)N * D * 2);
    ushort* y2     = (ushort*)take((size_t)N * D * 2);
    ushort* zbuf   = (ushort*)take((size_t)N * 1024 * 2);
    float*  x2     = (float*)take((size_t)N * D * 4);
    ushort* Wt     = (ushort*)take((size_t)13 * D * D * 2);
    int*    hist   = (int*)take((size_t)N * 4);
    int*    offs   = (int*)take((size_t)(N + 1) * 4);
    int*    cursor = (int*)take((size_t)N * 4);
    uint*   epack  = (uint*)take((size_t)E * 4);
    int*    permpad= (int*)take((size_t)(N + 256) * 4);
    int*    small  = (int*)take((size_t)(16 + gridMlp) * 4);
    int*    bsum   = (int*)take((size_t)scanB * 4);

    hipMemsetAsync(hist, 0, (size_t)N * 4, stream);
    hipMemsetAsync(small, 0, 16 * 4, stream);
    hipMemsetAsync(permpad, 0xFF, (size_t)(N + 256) * 4, stream);

    k_ln1<<<(N + 3) / 4, 256, 0, stream>>>(x, ntyp, conv_gamma, conv_beta, ybuf, N);
    k_cvt<<<13, 256, 0, stream>>>(W_rel, W_root, W_mlp, Wt);

    k_ehist<<<(E + 255) / 256, 256, 0, stream>>>(edst, hist, E);
    k_scan1<<<scanB, 256, 0, stream>>>(hist, bsum, N);
    k_scan2<<<1, 64, 0, stream>>>(bsum, offs, scanB, N);
    k_scan3<<<scanB, 256, 0, stream>>>(hist, bsum, offs, cursor, N);
    k_escatter<<<(E + 255) / 256, 256, 0, stream>>>(edst, esrc, etyp, cursor, epack, E);

    k_nhist<<<(N + 255) / 256, 256, 0, stream>>>(ntyp, small, N);
    k_prep<<<1, 256, 0, stream>>>(small, gridMlp);
    k_nscatter<<<(N + 255) / 256, 256, 0, stream>>>(ntyp, small, permpad, N);

    k_zagg<<<(N + 3) / 4, 256, 0, stream>>>(ybuf, offs, epack, zbuf, N);

    k_gemm2<<<(N + 63) / 64, 256, 0, stream>>>(ybuf, zbuf, Wt, x, ntyp,
                                               mlp_gamma, mlp_beta, x2, y2, N);

    k_mlp<<<gridMlp, 256, 0, stream>>>(y2, x2, permpad, small, Wt, b_mlp, out, N);
}